// Round 3
// baseline (1728.943 us; speedup 1.0000x reference)
//
#include <hip/hip_runtime.h>

static constexpr int T_LEN = 1024;

typedef float f32x2 __attribute__((ext_vector_type(2)));

__device__ __forceinline__ f32x2 fma2(f32x2 a, f32x2 b, f32x2 c) {
#if __has_builtin(__builtin_elementwise_fma)
    return __builtin_elementwise_fma(a, b, c);
#else
    f32x2 d; d.x = fmaf(a.x, b.x, c.x); d.y = fmaf(a.y, b.y, c.y); return d;
#endif
}

// 1/(1+2^t): overflow-safe (t->+inf: exp2=inf, rcp->0; t->-inf: ->1)
__device__ __forceinline__ float sig2(float t) {
    return __builtin_amdgcn_rcpf(1.f + __builtin_amdgcn_exp2f(t));
}
// broadcast/gather through the LDS-permute pipe (off the VALU)
__device__ __forceinline__ float bperm(int addr, float v) {
    return __int_as_float(__builtin_amdgcn_ds_bpermute(addr, __float_as_int(v)));
}

// One wave per batch element. Lane r = gi*16+j owns gate row r (PyTorch
// i,f,g,o order) of Whh0/Wih1 (packed as f32x2) and Whh1. Hidden unit j's
// state is replicated across the 4 gate groups, so ds_bpermute from lane k
// (k<16) broadcasts h[k]. Layer 2 runs two steps delayed via saved
// projection Xp so the two FMA chains are independent within an iteration.
__global__ void __launch_bounds__(256)
__attribute__((amdgpu_waves_per_eu(4, 4)))
lstm2_pk_kernel(
    const float* __restrict__ x,
    const float* __restrict__ Wih0, const float* __restrict__ Whh0,
    const float* __restrict__ bih0, const float* __restrict__ bhh0,
    const float* __restrict__ Wih1, const float* __restrict__ Whh1,
    const float* __restrict__ bih1, const float* __restrict__ bhh1,
    const float* __restrict__ Wout, const float* __restrict__ bout,
    float* __restrict__ out)
{
    const int tid  = threadIdx.x;
    const int lane = tid & 63;
    const int j    = lane & 15;
    const int gi   = lane >> 4;
    const int b    = blockIdx.x * 4 + (tid >> 6);

    // ---- per-lane weights into registers, then PIN them (asm results are
    // not rematerializable -> loads cannot be sunk into the T-loop).
    f32x2 w01[16];            // {Whh0[row][k], Wih1[row][k]}
    float w1r[16];            // Whh1[row][k]
#pragma unroll
    for (int q = 0; q < 4; ++q) {
        const float4 a = *reinterpret_cast<const float4*>(Whh0 + lane * 16 + q * 4);
        const float4 c = *reinterpret_cast<const float4*>(Wih1 + lane * 16 + q * 4);
        const float4 d = *reinterpret_cast<const float4*>(Whh1 + lane * 16 + q * 4);
        w01[q*4+0] = (f32x2){a.x, c.x}; w01[q*4+1] = (f32x2){a.y, c.y};
        w01[q*4+2] = (f32x2){a.z, c.z}; w01[q*4+3] = (f32x2){a.w, c.w};
        w1r[q*4+0] = d.x; w1r[q*4+1] = d.y; w1r[q*4+2] = d.z; w1r[q*4+3] = d.w;
    }
    float wi0 = Wih0[lane];
    float bb0 = bih0[lane] + bhh0[lane];
    float bb1 = bih1[lane] + bhh1[lane];
#pragma unroll
    for (int k = 0; k < 16; ++k)
        asm volatile("" : "+v"(w01[k]), "+v"(w1r[k]));
    asm volatile("" : "+v"(wi0), "+v"(bb0), "+v"(bb1));

    // opaque zero VGPR: bpermute base so constant lane indices fold into the
    // DS offset field instead of materializing 16 address movs.
    int zero;
    asm volatile("v_mov_b32 %0, 0" : "=v"(zero));
    const int aj = zero + (j << 2);   // gather base: lane j

    // activation constants: gate group 2 uses tanh = 2*sig(2v)-1
    const bool  isg  = (gi == 2);
    const float nsc  = isg ? -2.885390082f : -1.442695041f;  // -scale*log2e
    const float amul = isg ? 2.f : 1.f;
    const float aadd = isg ? -1.f : 0.f;
    const float NT   = -2.885390082f;

    float h1 = 0.f, c1 = 0.f, h2 = 0.f, c2 = 0.f, Xp = 0.f;

    const float* xb = x + (size_t)b * T_LEN;
    float4 xq = *reinterpret_cast<const float4*>(xb);

    for (int tb = 0; tb < T_LEN; tb += 4) {
        float4 xn = xq;
        if (tb + 4 < T_LEN)
            xn = *reinterpret_cast<const float4*>(xb + tb + 4);
#pragma unroll
        for (int u = 0; u < 4; ++u) {
            const int   t  = tb + u;
            const float xt = (u==0)?xq.x:(u==1)?xq.y:(u==2)?xq.z:xq.w;

            // layer-1 gates (A = .x) + projection of h1 for layer 2 (X = .y)
            f32x2 AX = fma2((f32x2){wi0, 0.f}, (f32x2){xt, xt},
                            (f32x2){bb0, bb1});
#pragma unroll
            for (int k = 0; k < 16; ++k) {
                const float hk = bperm(zero + 4 * k, h1);
                AX = fma2(w01[k], (f32x2){hk, hk}, AX);
            }

            // layer-2 step t-2 (independent chain)
            if (t >= 2) {
                float B = Xp;
#pragma unroll
                for (int k = 0; k < 16; ++k)
                    B = fmaf(w1r[k], bperm(zero + 4 * k, h2), B);
                const float act2 = fmaf(amul, sig2(nsc * B), aadd);
                const float i2 = bperm(aj,       act2);
                const float f2 = bperm(aj +  64, act2);
                const float g2 = bperm(aj + 128, act2);
                const float o2 = bperm(aj + 192, act2);
                c2 = fmaf(f2, c2, i2 * g2);
                h2 = o2 * fmaf(2.f, sig2(NT * c2), -1.f);
            }

            // layer-1 activation + update
            {
                const float act1 = fmaf(amul, sig2(nsc * AX.x), aadd);
                const float i1 = bperm(aj,       act1);
                const float f1 = bperm(aj +  64, act1);
                const float g1 = bperm(aj + 128, act1);
                const float o1 = bperm(aj + 192, act1);
                c1 = fmaf(f1, c1, i1 * g1);
                h1 = o1 * fmaf(2.f, sig2(NT * c1), -1.f);
            }
            Xp = AX.y;
        }
        xq = xn;
    }

    // epilogue: layer-2 steps T-2 (Xp, h2[T-3]) and T-1 (h1[T-1], h2[T-2])
#pragma unroll
    for (int e = 0; e < 2; ++e) {
        float B;
        if (e == 0) {
            B = Xp;
        } else {
            B = bb1;
#pragma unroll
            for (int k = 0; k < 16; ++k)
                B = fmaf(w01[k].y, bperm(zero + 4 * k, h1), B);
        }
#pragma unroll
        for (int k = 0; k < 16; ++k)
            B = fmaf(w1r[k], bperm(zero + 4 * k, h2), B);
        const float act2 = fmaf(amul, sig2(nsc * B), aadd);
        const float i2 = bperm(aj,       act2);
        const float f2 = bperm(aj +  64, act2);
        const float g2 = bperm(aj + 128, act2);
        const float o2 = bperm(aj + 192, act2);
        c2 = fmaf(f2, c2, i2 * g2);
        h2 = o2 * fmaf(2.f, sig2(NT * c2), -1.f);
    }

    // head: out[b][m] = relu(h2) . Wout[m] + bout[m]
    const float rh = fmaxf(h2, 0.f);
#pragma unroll
    for (int m = 0; m < 5; ++m) {
        float p = rh * Wout[m * 16 + j];
        p += __shfl_xor(p, 1, 16);
        p += __shfl_xor(p, 2, 16);
        p += __shfl_xor(p, 4, 16);
        p += __shfl_xor(p, 8, 16);
        if (lane == m) out[b * 5 + m] = p + bout[m];
    }
}

extern "C" void kernel_launch(void* const* d_in, const int* in_sizes, int n_in,
                              void* d_out, int out_size, void* d_ws, size_t ws_size,
                              hipStream_t stream) {
    const float* x    = (const float*)d_in[0];
    const float* Wih0 = (const float*)d_in[1];
    const float* Whh0 = (const float*)d_in[2];
    const float* bih0 = (const float*)d_in[3];
    const float* bhh0 = (const float*)d_in[4];
    const float* Wih1 = (const float*)d_in[5];
    const float* Whh1 = (const float*)d_in[6];
    const float* bih1 = (const float*)d_in[7];
    const float* bhh1 = (const float*)d_in[8];
    const float* Wout = (const float*)d_in[9];
    const float* bout = (const float*)d_in[10];
    float* out = (float*)d_out;

    const int B = in_sizes[0] / T_LEN;          // 4096
    dim3 grid(B / 4), block(256);               // 1 wave per sequence
    hipLaunchKernelGGL(lstm2_pk_kernel, grid, block, 0, stream,
                       x, Wih0, Whh0, bih0, bhh0,
                       Wih1, Whh1, bih1, bhh1, Wout, bout, out);
}

// Round 4
// 863.379 us; speedup vs baseline: 2.0025x; 2.0025x over previous
//
#include <hip/hip_runtime.h>

static constexpr int T_LEN = 1024;

// wave-uniform broadcast from literal lane (v_readlane_b32 -> SGPR operand)
__device__ __forceinline__ float bcastf(float v, int l) {
    return __uint_as_float(__builtin_amdgcn_readlane(__float_as_uint(v), l));
}
// 1/(1+2^t): overflow-safe (t->+inf: exp2=inf, rcp->0; t->-inf: ->1)
__device__ __forceinline__ float sig2(float t) {
    return __builtin_amdgcn_rcpf(1.f + __builtin_amdgcn_exp2f(t));
}
// gate gather through the LDS-permute pipe (only 8 of these per step)
__device__ __forceinline__ float bperm(int addr, float v) {
    return __int_as_float(__builtin_amdgcn_ds_bpermute(addr, __float_as_int(v)));
}

// One wave per batch element. Lane r = gi*16+j owns gate row r (PyTorch
// i,f,g,o order) of Whh0, Wih1, Whh1; weights live in PINNED VGPRs (asm
// results are not rematerializable, so loads cannot be sunk into the
// T-loop — round-3-verified). h broadcasts go through v_readlane (VALU,
// low latency); only the 4-gate gathers use ds_bpermute. Layer 2 runs two
// steps delayed via saved projection Xp so its FMA chain is independent
// of layer 1's within an iteration.
__global__ void __launch_bounds__(256)
__attribute__((amdgpu_waves_per_eu(4, 4)))
lstm2_rl_kernel(
    const float* __restrict__ x,
    const float* __restrict__ Wih0, const float* __restrict__ Whh0,
    const float* __restrict__ bih0, const float* __restrict__ bhh0,
    const float* __restrict__ Wih1, const float* __restrict__ Whh1,
    const float* __restrict__ bih1, const float* __restrict__ bhh1,
    const float* __restrict__ Wout, const float* __restrict__ bout,
    float* __restrict__ out)
{
    const int tid  = threadIdx.x;
    const int lane = tid & 63;
    const int j    = lane & 15;
    const int gi   = lane >> 4;
    const int b    = blockIdx.x * 4 + (tid >> 6);

    // ---- per-lane weight rows into registers, then PIN them.
    float w0r[16], wx1r[16], w1r[16];
#pragma unroll
    for (int q = 0; q < 4; ++q) {
        const float4 a = *reinterpret_cast<const float4*>(Whh0 + lane * 16 + q * 4);
        const float4 c = *reinterpret_cast<const float4*>(Wih1 + lane * 16 + q * 4);
        const float4 d = *reinterpret_cast<const float4*>(Whh1 + lane * 16 + q * 4);
        w0r[q*4+0]=a.x; w0r[q*4+1]=a.y; w0r[q*4+2]=a.z; w0r[q*4+3]=a.w;
        wx1r[q*4+0]=c.x; wx1r[q*4+1]=c.y; wx1r[q*4+2]=c.z; wx1r[q*4+3]=c.w;
        w1r[q*4+0]=d.x; w1r[q*4+1]=d.y; w1r[q*4+2]=d.z; w1r[q*4+3]=d.w;
    }
    float wi0 = Wih0[lane];
    float bb0 = bih0[lane] + bhh0[lane];
    float bb1 = bih1[lane] + bhh1[lane];
#pragma unroll
    for (int k = 0; k < 16; ++k)
        asm volatile("" : "+v"(w0r[k]), "+v"(wx1r[k]), "+v"(w1r[k]));
    asm volatile("" : "+v"(wi0), "+v"(bb0), "+v"(bb1));

    // opaque zero VGPR: bpermute base so the gather lane indices fold into
    // the DS offset field.
    int zero;
    asm volatile("v_mov_b32 %0, 0" : "=v"(zero));
    const int aj = zero + (j << 2);   // gather base: lane j

    // activation constants: gate group 2 uses tanh = 2*sig(2v)-1
    const bool  isg  = (gi == 2);
    const float nsc  = isg ? -2.885390082f : -1.442695041f;  // -scale*log2e
    const float amul = isg ? 2.f : 1.f;
    const float aadd = isg ? -1.f : 0.f;
    const float NT   = -2.885390082f;

    float h1 = 0.f, c1 = 0.f, h2 = 0.f, c2 = 0.f, Xp = 0.f;

    const float* xb = x + (size_t)b * T_LEN;
    float4 xq = *reinterpret_cast<const float4*>(xb);

    for (int tb = 0; tb < T_LEN; tb += 4) {
        float4 xn = xq;
        if (tb + 4 < T_LEN)
            xn = *reinterpret_cast<const float4*>(xb + tb + 4);
#pragma unroll
        for (int u = 0; u < 4; ++u) {
            const int   t  = tb + u;
            const float xt = (u==0)?xq.x:(u==1)?xq.y:(u==2)?xq.z:xq.w;

            // layer-1 gates (A) + projection of h1 for layer 2 (X);
            // one readlane feeds both FMAs.
            float A = fmaf(wi0, xt, bb0);
            float X = bb1;
#pragma unroll
            for (int k = 0; k < 16; ++k) {
                const float hk = bcastf(h1, k);
                A = fmaf(w0r[k],  hk, A);
                X = fmaf(wx1r[k], hk, X);
            }

            // layer-2 step t-2 (independent chain; interleaves with above)
            if (t >= 2) {
                float B = Xp;
#pragma unroll
                for (int k = 0; k < 16; ++k)
                    B = fmaf(w1r[k], bcastf(h2, k), B);
                const float act2 = fmaf(amul, sig2(nsc * B), aadd);
                const float i2 = bperm(aj,       act2);
                const float f2 = bperm(aj +  64, act2);
                const float g2 = bperm(aj + 128, act2);
                const float o2 = bperm(aj + 192, act2);
                c2 = fmaf(f2, c2, i2 * g2);
                h2 = o2 * fmaf(2.f, sig2(NT * c2), -1.f);
            }

            // layer-1 activation + update
            {
                const float act1 = fmaf(amul, sig2(nsc * A), aadd);
                const float i1 = bperm(aj,       act1);
                const float f1 = bperm(aj +  64, act1);
                const float g1 = bperm(aj + 128, act1);
                const float o1 = bperm(aj + 192, act1);
                c1 = fmaf(f1, c1, i1 * g1);
                h1 = o1 * fmaf(2.f, sig2(NT * c1), -1.f);
            }
            Xp = X;
        }
        xq = xn;
    }

    // epilogue: layer-2 steps T-2 (Xp, h2[T-3]) and T-1 (h1[T-1], h2[T-2])
#pragma unroll
    for (int e = 0; e < 2; ++e) {
        float B;
        if (e == 0) {
            B = Xp;
        } else {
            B = bb1;
#pragma unroll
            for (int k = 0; k < 16; ++k)
                B = fmaf(wx1r[k], bcastf(h1, k), B);
        }
#pragma unroll
        for (int k = 0; k < 16; ++k)
            B = fmaf(w1r[k], bcastf(h2, k), B);
        const float act2 = fmaf(amul, sig2(nsc * B), aadd);
        const float i2 = bperm(aj,       act2);
        const float f2 = bperm(aj +  64, act2);
        const float g2 = bperm(aj + 128, act2);
        const float o2 = bperm(aj + 192, act2);
        c2 = fmaf(f2, c2, i2 * g2);
        h2 = o2 * fmaf(2.f, sig2(NT * c2), -1.f);
    }

    // head: out[b][m] = relu(h2) . Wout[m] + bout[m]
    const float rh = fmaxf(h2, 0.f);
#pragma unroll
    for (int m = 0; m < 5; ++m) {
        float p = rh * Wout[m * 16 + j];
        p += __shfl_xor(p, 1, 16);
        p += __shfl_xor(p, 2, 16);
        p += __shfl_xor(p, 4, 16);
        p += __shfl_xor(p, 8, 16);
        if (lane == m) out[b * 5 + m] = p + bout[m];
    }
}

extern "C" void kernel_launch(void* const* d_in, const int* in_sizes, int n_in,
                              void* d_out, int out_size, void* d_ws, size_t ws_size,
                              hipStream_t stream) {
    const float* x    = (const float*)d_in[0];
    const float* Wih0 = (const float*)d_in[1];
    const float* Whh0 = (const float*)d_in[2];
    const float* bih0 = (const float*)d_in[3];
    const float* bhh0 = (const float*)d_in[4];
    const float* Wih1 = (const float*)d_in[5];
    const float* Whh1 = (const float*)d_in[6];
    const float* bih1 = (const float*)d_in[7];
    const float* bhh1 = (const float*)d_in[8];
    const float* Wout = (const float*)d_in[9];
    const float* bout = (const float*)d_in[10];
    float* out = (float*)d_out;

    const int B = in_sizes[0] / T_LEN;          // 4096
    dim3 grid(B / 4), block(256);               // 1 wave per sequence
    hipLaunchKernelGGL(lstm2_rl_kernel, grid, block, 0, stream,
                       x, Wih0, Whh0, bih0, bhh0,
                       Wih1, Whh1, bih1, bhh1, Wout, bout, out);
}